// Round 1
// baseline (1032.557 us; speedup 1.0000x reference)
//
#include <hip/hip_runtime.h>

#define TT 2048
#define BB 2
#define EE 1024
#define HH 16
#define DD 64
#define E3 3072
#define NTOK 4096

// C[M,N] = A[M,K] @ W[N,K]^T + bias[N]   (both operands K-contiguous, "NT")
// 128x128 tile, BK=16, 256 threads, 8x8 microtile as 2x2 blocks of 4x4.
__global__ __launch_bounds__(256) void gemm_nt_bias(
    const float* __restrict__ A, const float* __restrict__ W,
    const float* __restrict__ bias, float* __restrict__ C,
    int M, int N, int K)
{
    __shared__ float As[16][132];   // [k][m], pad 132 (528B rows, 16B aligned)
    __shared__ float Bs[16][132];   // [k][n]

    const int tid = threadIdx.x;
    const int tx = tid & 15;        // 16 col groups
    const int ty = tid >> 4;        // 16 row groups
    const int m0 = blockIdx.y << 7;
    const int n0 = blockIdx.x << 7;

    // load mapping: thread -> (row = tid/2, 8 contiguous k at (tid&1)*8)
    const int lrow = tid >> 1;
    const int lk8  = (tid & 1) << 3;
    const float* Ald = A + (size_t)(m0 + lrow) * K + lk8;
    const float* Wld = W + (size_t)(n0 + lrow) * K + lk8;

    float acc[8][8];
#pragma unroll
    for (int i = 0; i < 8; ++i)
#pragma unroll
        for (int j = 0; j < 8; ++j) acc[i][j] = 0.f;

    for (int k0 = 0; k0 < K; k0 += 16) {
        float4 a0 = *(const float4*)(Ald + k0);
        float4 a1 = *(const float4*)(Ald + k0 + 4);
        float4 b0 = *(const float4*)(Wld + k0);
        float4 b1 = *(const float4*)(Wld + k0 + 4);
        __syncthreads();   // previous iteration's readers done
        As[lk8 + 0][lrow] = a0.x; As[lk8 + 1][lrow] = a0.y;
        As[lk8 + 2][lrow] = a0.z; As[lk8 + 3][lrow] = a0.w;
        As[lk8 + 4][lrow] = a1.x; As[lk8 + 5][lrow] = a1.y;
        As[lk8 + 6][lrow] = a1.z; As[lk8 + 7][lrow] = a1.w;
        Bs[lk8 + 0][lrow] = b0.x; Bs[lk8 + 1][lrow] = b0.y;
        Bs[lk8 + 2][lrow] = b0.z; Bs[lk8 + 3][lrow] = b0.w;
        Bs[lk8 + 4][lrow] = b1.x; Bs[lk8 + 5][lrow] = b1.y;
        Bs[lk8 + 6][lrow] = b1.z; Bs[lk8 + 7][lrow] = b1.w;
        __syncthreads();
#pragma unroll
        for (int k = 0; k < 16; ++k) {
            float4 xa0 = *(const float4*)&As[k][ty * 4];
            float4 xa1 = *(const float4*)&As[k][64 + ty * 4];
            float4 xb0 = *(const float4*)&Bs[k][tx * 4];
            float4 xb1 = *(const float4*)&Bs[k][64 + tx * 4];
            float av[8] = {xa0.x, xa0.y, xa0.z, xa0.w,
                           xa1.x, xa1.y, xa1.z, xa1.w};
            float bv[8] = {xb0.x, xb0.y, xb0.z, xb0.w,
                           xb1.x, xb1.y, xb1.z, xb1.w};
#pragma unroll
            for (int i = 0; i < 8; ++i)
#pragma unroll
                for (int j = 0; j < 8; ++j)
                    acc[i][j] = fmaf(av[i], bv[j], acc[i][j]);
        }
    }

    float4 bj0 = *(const float4*)&bias[n0 + tx * 4];
    float4 bj1 = *(const float4*)&bias[n0 + 64 + tx * 4];
    float bb[8] = {bj0.x, bj0.y, bj0.z, bj0.w, bj1.x, bj1.y, bj1.z, bj1.w};

#pragma unroll
    for (int hi = 0; hi < 2; ++hi) {
#pragma unroll
        for (int i = 0; i < 4; ++i) {
            int row = m0 + hi * 64 + ty * 4 + i;
            float* cp = C + (size_t)row * N + n0;
            int ai = hi * 4 + i;
            float4 o0 = {acc[ai][0] + bb[0], acc[ai][1] + bb[1],
                         acc[ai][2] + bb[2], acc[ai][3] + bb[3]};
            float4 o1 = {acc[ai][4] + bb[4], acc[ai][5] + bb[5],
                         acc[ai][6] + bb[6], acc[ai][7] + bb[7]};
            *(float4*)(cp + tx * 4) = o0;
            *(float4*)(cp + 64 + tx * 4) = o1;
        }
    }
}

// Flash attention, fp32. One block per (b, h, 64-query tile). 256 threads.
// Thread (ty = tid/16, tx = tid%16) owns 4x4 microtile: rows ty*4+i, cols tx*4+j.
// qkv layout: [B*T, 3E]; q cols [h*D, ...), k cols [E + h*D, ...), v [2E + h*D, ...)
__global__ __launch_bounds__(256) void attn_kernel(
    const float* __restrict__ qkv, float* __restrict__ out)
{
    __shared__ float Qt[64][68];   // [d][q]  transposed
    __shared__ float Kt[64][68];   // [d][k]  transposed
    __shared__ float Vs[64][68];   // [k][d]  straight (rows 272B, 16B aligned)
    __shared__ float Pt[64][68];   // [k][q]  transposed probabilities

    const int tid = threadIdx.x;
    const int tx = tid & 15;
    const int ty = tid >> 4;
    const int q0 = blockIdx.x * 64;
    const int h  = blockIdx.y;
    const int b  = blockIdx.z;
    const float scale = 0.125f;    // 1/sqrt(64)

    const size_t baseQ = (size_t)b * TT * E3 + (size_t)h * DD;
    const size_t baseK = baseQ + EE;
    const size_t baseV = baseQ + 2 * EE;

    // load+transpose Q tile: f in [0,1024): row=f/16, c4=f%16
#pragma unroll
    for (int i = 0; i < 4; ++i) {
        int f = tid + 256 * i;
        int row = f >> 4, c4 = f & 15;
        float4 v = *(const float4*)&qkv[baseQ + (size_t)(q0 + row) * E3 + c4 * 4];
        Qt[c4 * 4 + 0][row] = v.x; Qt[c4 * 4 + 1][row] = v.y;
        Qt[c4 * 4 + 2][row] = v.z; Qt[c4 * 4 + 3][row] = v.w;
    }

    float m_i[4], l_i[4], acc[4][4];
#pragma unroll
    for (int i = 0; i < 4; ++i) {
        m_i[i] = -1e30f; l_i[i] = 0.f;
#pragma unroll
        for (int j = 0; j < 4; ++j) acc[i][j] = 0.f;
    }

    for (int kt = 0; kt < TT; kt += 64) {
        __syncthreads();   // prev PV readers of Kt/Vs done (also: nothing on iter 0)
#pragma unroll
        for (int i = 0; i < 4; ++i) {
            int f = tid + 256 * i;
            int row = f >> 4, c4 = f & 15;
            float4 kv = *(const float4*)&qkv[baseK + (size_t)(kt + row) * E3 + c4 * 4];
            Kt[c4 * 4 + 0][row] = kv.x; Kt[c4 * 4 + 1][row] = kv.y;
            Kt[c4 * 4 + 2][row] = kv.z; Kt[c4 * 4 + 3][row] = kv.w;
            float4 vv = *(const float4*)&qkv[baseV + (size_t)(kt + row) * E3 + c4 * 4];
            *(float4*)&Vs[row][c4 * 4] = vv;
        }
        __syncthreads();   // K/V (and Q on iter 0) visible

        // S = scale * Q K^T  (4x4 microtile per thread)
        float s[4][4];
#pragma unroll
        for (int i = 0; i < 4; ++i)
#pragma unroll
            for (int j = 0; j < 4; ++j) s[i][j] = 0.f;
#pragma unroll 16
        for (int d = 0; d < 64; ++d) {
            float4 qa = *(const float4*)&Qt[d][ty * 4];
            float4 kb = *(const float4*)&Kt[d][tx * 4];
            float qv[4] = {qa.x, qa.y, qa.z, qa.w};
            float kv[4] = {kb.x, kb.y, kb.z, kb.w};
#pragma unroll
            for (int i = 0; i < 4; ++i)
#pragma unroll
                for (int j = 0; j < 4; ++j)
                    s[i][j] = fmaf(qv[i], kv[j], s[i][j]);
        }

        // online softmax per row (16 lanes/row share ty group; lanes consecutive)
        float alpha[4];
#pragma unroll
        for (int i = 0; i < 4; ++i) {
            float mt = fmaxf(fmaxf(s[i][0] * scale, s[i][1] * scale),
                             fmaxf(s[i][2] * scale, s[i][3] * scale));
#pragma unroll
            for (int off = 1; off < 16; off <<= 1)
                mt = fmaxf(mt, __shfl_xor(mt, off, 64));
            float mnew = fmaxf(m_i[i], mt);
            alpha[i] = __expf(m_i[i] - mnew);
            float rsum = 0.f;
#pragma unroll
            for (int j = 0; j < 4; ++j) {
                float p = __expf(s[i][j] * scale - mnew);
                s[i][j] = p;
                rsum += p;
            }
#pragma unroll
            for (int off = 1; off < 16; off <<= 1)
                rsum += __shfl_xor(rsum, off, 64);
            l_i[i] = l_i[i] * alpha[i] + rsum;
            m_i[i] = mnew;
            // store P transposed: Pt[col][row]
#pragma unroll
            for (int j = 0; j < 4; ++j)
                Pt[tx * 4 + j][ty * 4 + i] = s[i][j];
        }
        // rescale accumulator
#pragma unroll
        for (int i = 0; i < 4; ++i)
#pragma unroll
            for (int j = 0; j < 4; ++j) acc[i][j] *= alpha[i];

        __syncthreads();   // Pt visible to all

        // O += P @ V   (over 64 keys)
#pragma unroll 16
        for (int kk = 0; kk < 64; ++kk) {
            float4 pa = *(const float4*)&Pt[kk][ty * 4];
            float4 vb = *(const float4*)&Vs[kk][tx * 4];
            float pv[4] = {pa.x, pa.y, pa.z, pa.w};
            float vv[4] = {vb.x, vb.y, vb.z, vb.w};
#pragma unroll
            for (int i = 0; i < 4; ++i)
#pragma unroll
                for (int j = 0; j < 4; ++j)
                    acc[i][j] = fmaf(pv[i], vv[j], acc[i][j]);
        }
    }

    // epilogue: normalize and store to [B*T, E] with head offset
#pragma unroll
    for (int i = 0; i < 4; ++i) {
        float inv = 1.f / l_i[i];
        int row = q0 + ty * 4 + i;
        float4 o = {acc[i][0] * inv, acc[i][1] * inv,
                    acc[i][2] * inv, acc[i][3] * inv};
        *(float4*)&out[((size_t)(b * TT + row)) * EE + h * DD + tx * 4] = o;
    }
}

extern "C" void kernel_launch(void* const* d_in, const int* in_sizes, int n_in,
                              void* d_out, int out_size, void* d_ws, size_t ws_size,
                              hipStream_t stream)
{
    const float* x     = (const float*)d_in[0];
    const float* qkv_w = (const float*)d_in[1];
    const float* qkv_b = (const float*)d_in[2];
    const float* out_w = (const float*)d_in[3];
    const float* out_b = (const float*)d_in[4];
    float* out = (float*)d_out;

    float* qkvbuf  = (float*)d_ws;                        // 4096*3072 fp32 = 50.3 MB
    float* attnbuf = qkvbuf + (size_t)NTOK * E3;          // 4096*1024 fp32 = 16.8 MB

    // qkv = x @ qkv_w^T + qkv_b
    gemm_nt_bias<<<dim3(E3 / 128, NTOK / 128), 256, 0, stream>>>(
        x, qkv_w, qkv_b, qkvbuf, NTOK, E3, EE);
    // per-head flash attention
    attn_kernel<<<dim3(TT / 64, HH, BB), 256, 0, stream>>>(qkvbuf, attnbuf);
    // out = attn @ out_w^T + out_b
    gemm_nt_bias<<<dim3(EE / 128, NTOK / 128), 256, 0, stream>>>(
        attnbuf, out_w, out_b, out, NTOK, EE, EE);
}

// Round 2
// 619.081 us; speedup vs baseline: 1.6679x; 1.6679x over previous
//
#include <hip/hip_runtime.h>

#define TT 2048
#define BB 2
#define EE 1024
#define HH 16
#define DD 64
#define E3 3072
#define NTOK 4096

typedef unsigned short u16;
typedef __attribute__((ext_vector_type(8))) short short8;
typedef __attribute__((ext_vector_type(4))) float f32x4;

__device__ inline u16 f2bf(float f) {
    union { float f; unsigned u; } v; v.f = f;
    unsigned r = (v.u + 0x7fffu + ((v.u >> 16) & 1u)) >> 16;
    return (u16)r;
}
__device__ inline unsigned pack2(float a, float b) {
    return (unsigned)f2bf(a) | ((unsigned)f2bf(b) << 16);
}

// C[M,N] = A[M,K] @ W[N,K]^T + bias[N]   (fp32 compute)
// 128x128 tile, BK=16, 256 threads, 8x8 microtile. BF16_OUT selects epilogue dtype.
template <bool BF16_OUT>
__global__ __launch_bounds__(256) void gemm_nt_bias(
    const float* __restrict__ A, const float* __restrict__ W,
    const float* __restrict__ bias, void* __restrict__ Cout,
    int M, int N, int K)
{
    __shared__ float As[16][132];
    __shared__ float Bs[16][132];

    const int tid = threadIdx.x;
    const int tx = tid & 15;
    const int ty = tid >> 4;
    const int m0 = blockIdx.y << 7;
    const int n0 = blockIdx.x << 7;

    const int lrow = tid >> 1;
    const int lk8  = (tid & 1) << 3;
    const float* Ald = A + (size_t)(m0 + lrow) * K + lk8;
    const float* Wld = W + (size_t)(n0 + lrow) * K + lk8;

    float acc[8][8];
#pragma unroll
    for (int i = 0; i < 8; ++i)
#pragma unroll
        for (int j = 0; j < 8; ++j) acc[i][j] = 0.f;

    for (int k0 = 0; k0 < K; k0 += 16) {
        float4 a0 = *(const float4*)(Ald + k0);
        float4 a1 = *(const float4*)(Ald + k0 + 4);
        float4 b0 = *(const float4*)(Wld + k0);
        float4 b1 = *(const float4*)(Wld + k0 + 4);
        __syncthreads();
        As[lk8 + 0][lrow] = a0.x; As[lk8 + 1][lrow] = a0.y;
        As[lk8 + 2][lrow] = a0.z; As[lk8 + 3][lrow] = a0.w;
        As[lk8 + 4][lrow] = a1.x; As[lk8 + 5][lrow] = a1.y;
        As[lk8 + 6][lrow] = a1.z; As[lk8 + 7][lrow] = a1.w;
        Bs[lk8 + 0][lrow] = b0.x; Bs[lk8 + 1][lrow] = b0.y;
        Bs[lk8 + 2][lrow] = b0.z; Bs[lk8 + 3][lrow] = b0.w;
        Bs[lk8 + 4][lrow] = b1.x; Bs[lk8 + 5][lrow] = b1.y;
        Bs[lk8 + 6][lrow] = b1.z; Bs[lk8 + 7][lrow] = b1.w;
        __syncthreads();
#pragma unroll
        for (int k = 0; k < 16; ++k) {
            float4 xa0 = *(const float4*)&As[k][ty * 4];
            float4 xa1 = *(const float4*)&As[k][64 + ty * 4];
            float4 xb0 = *(const float4*)&Bs[k][tx * 4];
            float4 xb1 = *(const float4*)&Bs[k][64 + tx * 4];
            float av[8] = {xa0.x, xa0.y, xa0.z, xa0.w,
                           xa1.x, xa1.y, xa1.z, xa1.w};
            float bv[8] = {xb0.x, xb0.y, xb0.z, xb0.w,
                           xb1.x, xb1.y, xb1.z, xb1.w};
#pragma unroll
            for (int i = 0; i < 8; ++i)
#pragma unroll
                for (int j = 0; j < 8; ++j)
                    acc[i][j] = fmaf(av[i], bv[j], acc[i][j]);
        }
    }

    float4 bj0 = *(const float4*)&bias[n0 + tx * 4];
    float4 bj1 = *(const float4*)&bias[n0 + 64 + tx * 4];
    float bb[8] = {bj0.x, bj0.y, bj0.z, bj0.w, bj1.x, bj1.y, bj1.z, bj1.w};

#pragma unroll
    for (int hi = 0; hi < 2; ++hi) {
#pragma unroll
        for (int i = 0; i < 4; ++i) {
            int row = m0 + hi * 64 + ty * 4 + i;
            int ai = hi * 4 + i;
            float o[8];
#pragma unroll
            for (int j = 0; j < 8; ++j) o[j] = acc[ai][j] + bb[j];
            if (BF16_OUT) {
                u16* cp = (u16*)Cout + (size_t)row * N + n0;
                uint2 p0 = {pack2(o[0], o[1]), pack2(o[2], o[3])};
                uint2 p1 = {pack2(o[4], o[5]), pack2(o[6], o[7])};
                *(uint2*)(cp + tx * 4) = p0;
                *(uint2*)(cp + 64 + tx * 4) = p1;
            } else {
                float* cp = (float*)Cout + (size_t)row * N + n0;
                float4 o0 = {o[0], o[1], o[2], o[3]};
                float4 o1 = {o[4], o[5], o[6], o[7]};
                *(float4*)(cp + tx * 4) = o0;
                *(float4*)(cp + 64 + tx * 4) = o1;
            }
        }
    }
}

// MFMA bf16 flash attention. Block = 256 thr = 4 waves, 64-query tile.
// Wave w owns S/O rows [16w, 16w+16). 16x16x32 bf16 MFMA.
// A-frag: A[m=lane&15][k=quad*8+j]; B-frag: B[k=quad*8+j][n=lane&15];
// C-frag: row=quad*4+reg, col=lane&15.  (m89/m91/m120 verified layouts)
__global__ __launch_bounds__(256) void attn_mfma(
    const u16* __restrict__ qkv, float* __restrict__ out)
{
    __shared__ u16 Qs[64][72];   // [q][d]       rows 144 B (16B-aligned)
    __shared__ u16 Ks[64][72];   // [key][d]
    __shared__ u16 Vt[64][72];   // [d][key^sw]  transposed + XOR-swizzled
    __shared__ u16 Ps[64][72];   // [q][key]

    const int tid  = threadIdx.x;
    const int wave = tid >> 6;
    const int lane = tid & 63;
    const int quad = lane >> 4;
    const int l16  = lane & 15;
    const int mq   = wave * 16;

    const int q0 = blockIdx.x * 64;
    const int h  = blockIdx.y;
    const int b  = blockIdx.z;
    const float scale = 0.125f;

    // staging map: thread -> (row = tid/4, 16 bf16 at col (tid%4)*16)
    const int ldrow = tid >> 2;
    const int ldc   = (tid & 3) << 4;
    // V transpose swizzle: key block (key>>3) XOR'd with (d>>4)&3 keeps
    // b128 reads contiguous while spreading the 2B transpose-writes 4x in banks
    const int vsw = (((ldrow >> 3) ^ (tid & 3)) << 3) | (ldrow & 7);

    // ---- load Q tile once ----
    {
        const u16* qp = qkv + (size_t)(b * TT + q0 + ldrow) * E3 + h * DD + ldc;
        *(uint4*)&Qs[ldrow][ldc]     = *(const uint4*)qp;
        *(uint4*)&Qs[ldrow][ldc + 8] = *(const uint4*)(qp + 8);
    }

    float m_i[4], l_i[4];
    f32x4 o[4];
#pragma unroll
    for (int r = 0; r < 4; ++r) { m_i[r] = -1e30f; l_i[r] = 0.f; }
#pragma unroll
    for (int dt = 0; dt < 4; ++dt) o[dt] = (f32x4){0.f, 0.f, 0.f, 0.f};

    for (int kt = 0; kt < TT; kt += 64) {
        __syncthreads();   // prior PV reads of Ks/Vt/Ps done
        const u16* kp = qkv + (size_t)(b * TT + kt + ldrow) * E3 + EE + h * DD + ldc;
        uint4 k0 = *(const uint4*)kp;
        uint4 k1 = *(const uint4*)(kp + 8);
        union { uint4 u[2]; u16 s[16]; } vv;
        vv.u[0] = *(const uint4*)(kp + EE);
        vv.u[1] = *(const uint4*)(kp + EE + 8);
        *(uint4*)&Ks[ldrow][ldc]     = k0;
        *(uint4*)&Ks[ldrow][ldc + 8] = k1;
#pragma unroll
        for (int j = 0; j < 16; ++j) Vt[ldc + j][vsw] = vv.s[j];
        __syncthreads();   // K/V staged

        // ---- S = Q K^T (16x64 strip per wave) ----
        f32x4 s[4];
#pragma unroll
        for (int nt = 0; nt < 4; ++nt) s[nt] = (f32x4){0.f, 0.f, 0.f, 0.f};
#pragma unroll
        for (int ks = 0; ks < 2; ++ks) {
            short8 aq = *(const short8*)&Qs[mq + l16][ks * 32 + quad * 8];
#pragma unroll
            for (int nt = 0; nt < 4; ++nt) {
                short8 bk = *(const short8*)&Ks[nt * 16 + l16][ks * 32 + quad * 8];
                s[nt] = __builtin_amdgcn_mfma_f32_16x16x32_bf16(aq, bk, s[nt], 0, 0, 0);
            }
        }

        // ---- online softmax on 4 owned rows ----
#pragma unroll
        for (int r = 0; r < 4; ++r) {
            float mt = fmaxf(fmaxf(s[0][r], s[1][r]), fmaxf(s[2][r], s[3][r])) * scale;
#pragma unroll
            for (int off = 1; off < 16; off <<= 1)
                mt = fmaxf(mt, __shfl_xor(mt, off, 64));
            float mnew = fmaxf(m_i[r], mt);
            float alpha = __expf(m_i[r] - mnew);
            m_i[r] = mnew;
            float p0 = __expf(s[0][r] * scale - mnew);
            float p1 = __expf(s[1][r] * scale - mnew);
            float p2 = __expf(s[2][r] * scale - mnew);
            float p3 = __expf(s[3][r] * scale - mnew);
            float rs = (p0 + p1) + (p2 + p3);
#pragma unroll
            for (int off = 1; off < 16; off <<= 1)
                rs += __shfl_xor(rs, off, 64);
            l_i[r] = l_i[r] * alpha + rs;
            int prow = mq + quad * 4 + r;
            Ps[prow][l16]      = f2bf(p0);
            Ps[prow][16 + l16] = f2bf(p1);
            Ps[prow][32 + l16] = f2bf(p2);
            Ps[prow][48 + l16] = f2bf(p3);
            o[0][r] *= alpha; o[1][r] *= alpha;
            o[2][r] *= alpha; o[3][r] *= alpha;
        }
        __syncthreads();   // Ps visible

        // ---- O += P V ----
#pragma unroll
        for (int ks = 0; ks < 2; ++ks) {
            short8 ap = *(const short8*)&Ps[mq + l16][ks * 32 + quad * 8];
#pragma unroll
            for (int dt = 0; dt < 4; ++dt) {
                short8 bv = *(const short8*)&Vt[dt * 16 + l16][ks * 32 + ((quad ^ dt) << 3)];
                o[dt] = __builtin_amdgcn_mfma_f32_16x16x32_bf16(ap, bv, o[dt], 0, 0, 0);
            }
        }
    }

    // ---- epilogue: normalize, store fp32 ----
#pragma unroll
    for (int r = 0; r < 4; ++r) {
        float inv = 1.f / l_i[r];
        float* op = out + (size_t)(b * TT + q0 + mq + quad * 4 + r) * EE + h * DD;
        op[l16]      = o[0][r] * inv;
        op[16 + l16] = o[1][r] * inv;
        op[32 + l16] = o[2][r] * inv;
        op[48 + l16] = o[3][r] * inv;
    }
}

extern "C" void kernel_launch(void* const* d_in, const int* in_sizes, int n_in,
                              void* d_out, int out_size, void* d_ws, size_t ws_size,
                              hipStream_t stream)
{
    const float* x     = (const float*)d_in[0];
    const float* qkv_w = (const float*)d_in[1];
    const float* qkv_b = (const float*)d_in[2];
    const float* out_w = (const float*)d_in[3];
    const float* out_b = (const float*)d_in[4];
    float* out = (float*)d_out;

    u16*   qkvbuf  = (u16*)d_ws;                               // 4096*3072 bf16 = 25.2 MB
    float* attnbuf = (float*)((char*)d_ws + (size_t)NTOK * E3 * sizeof(u16) + 256);

    gemm_nt_bias<true><<<dim3(E3 / 128, NTOK / 128), 256, 0, stream>>>(
        x, qkv_w, qkv_b, (void*)qkvbuf, NTOK, E3, EE);
    attn_mfma<<<dim3(TT / 64, HH, BB), 256, 0, stream>>>(qkvbuf, attnbuf);
    gemm_nt_bias<false><<<dim3(EE / 128, NTOK / 128), 256, 0, stream>>>(
        attnbuf, out_w, out_b, (void*)out, NTOK, EE, EE);
}

// Round 3
// 355.087 us; speedup vs baseline: 2.9079x; 1.7435x over previous
//
#include <hip/hip_runtime.h>

#define TT 2048
#define BB 2
#define EE 1024
#define HH 16
#define DD 64
#define E3 3072
#define NTOK 4096

typedef unsigned short u16;
typedef __attribute__((ext_vector_type(8))) short short8;
typedef __attribute__((ext_vector_type(4))) float f32x4;

__device__ __forceinline__ u16 f2bf(float f) {
    union { float f; unsigned u; } v; v.f = f;
    unsigned r = (v.u + 0x7fffu + ((v.u >> 16) & 1u)) >> 16;
    return (u16)r;
}
__device__ __forceinline__ float bf2f(u16 h) {
    union { unsigned u; float f; } v; v.u = ((unsigned)h) << 16; return v.f;
}

// async global->LDS, 16 B per lane; lds ptr must be wave-uniform (CK-style casts)
__device__ __forceinline__ void async_ld16(const u16* g, const u16* l) {
    auto gp = reinterpret_cast<const __attribute__((address_space(1))) unsigned*>(
        reinterpret_cast<uintptr_t>(g));
    auto lp = reinterpret_cast<__attribute__((address_space(3))) unsigned*>(
        reinterpret_cast<uintptr_t>(l));
    __builtin_amdgcn_global_load_lds(gp, lp, 16, 0, 0);
}

// fp32 -> (hi, lo) bf16 planar split, float4 per thread
__global__ __launch_bounds__(256) void split_hl(
    const float* __restrict__ in, u16* __restrict__ hi, u16* __restrict__ lo, int n4)
{
    int i = blockIdx.x * 256 + threadIdx.x;
    if (i >= n4) return;
    float4 v = ((const float4*)in)[i];
    float vv[4] = {v.x, v.y, v.z, v.w};
    unsigned hp[2], lp[2];
#pragma unroll
    for (int p = 0; p < 2; ++p) {
        u16 h0 = f2bf(vv[2 * p]);
        u16 h1 = f2bf(vv[2 * p + 1]);
        u16 l0 = f2bf(vv[2 * p] - bf2f(h0));
        u16 l1 = f2bf(vv[2 * p + 1] - bf2f(h1));
        hp[p] = (unsigned)h0 | ((unsigned)h1 << 16);
        lp[p] = (unsigned)l0 | ((unsigned)l1 << 16);
    }
    *(uint2*)&hi[(size_t)i * 4] = make_uint2(hp[0], hp[1]);
    *(uint2*)&lo[(size_t)i * 4] = make_uint2(lp[0], lp[1]);
}

// Split-bf16 MFMA GEMM:  C[M,N] = A[M,K=1024] @ W[N,K=1024]^T + bias
// A,W given as planar (hi,lo) bf16.  C ~= Ah*Wh + Al*Wh + Ah*Wl  (3 MFMA passes)
// Block: 256 thr = 4 waves (2x2). BN=128. BM = WMT*32 (WMT m-tiles of 16 per wave).
// LDS XOR swizzle: phys_k8 = k8 ^ ((row>>1)&3) -> contiguous global_load_lds writes
// (permute the GLOBAL source index, not the LDS dest) + <=2-way ds_read_b128 banks.
template <int WMT, bool BF16OUT>
__global__ __launch_bounds__(256) void gemm_hilo_mfma(
    const u16* __restrict__ Ahg, const u16* __restrict__ Alg,
    const u16* __restrict__ Whg, const u16* __restrict__ Wlg,
    const float* __restrict__ bias, void* __restrict__ Cout, int M, int N)
{
    constexpr int BM = WMT * 32;
    constexpr int AHALF = BM / 64;          // global_load_lds passes for A (2 or 1)
    __shared__ u16 sAh[BM * 32], sAl[BM * 32];
    __shared__ u16 sBh[128 * 32], sBl[128 * 32];

    const int tid  = threadIdx.x;
    const int lane = tid & 63;
    const int wave = tid >> 6;
    const int quad = lane >> 4;
    const int l16  = lane & 15;
    const int wm = wave >> 1, wn = wave & 1;
    const int m0 = blockIdx.y * BM;
    const int n0 = blockIdx.x * 128;

    // ---- staging maps: slot s = pass*256 + tid; LDS byte = s*16 (contiguous) ----
    const u16* agh[AHALF]; const u16* agl[AHALF]; int aldw[AHALF];
#pragma unroll
    for (int h = 0; h < AHALF; ++h) {
        int s = h * 256 + tid;
        int row = s >> 2, k8p = s & 3;
        int k8 = k8p ^ ((row >> 1) & 3);
        agh[h] = Ahg + (size_t)(m0 + row) * EE + k8 * 8;
        agl[h] = Alg + (size_t)(m0 + row) * EE + k8 * 8;
        aldw[h] = (h * 256 + wave * 64) * 8;    // wave-uniform u16 offset
    }
    const u16* bgh[2]; const u16* bgl[2]; int bldw[2];
#pragma unroll
    for (int h = 0; h < 2; ++h) {
        int s = h * 256 + tid;
        int row = s >> 2, k8p = s & 3;
        int k8 = k8p ^ ((row >> 1) & 3);
        bgh[h] = Whg + (size_t)(n0 + row) * EE + k8 * 8;
        bgl[h] = Wlg + (size_t)(n0 + row) * EE + k8 * 8;
        bldw[h] = (h * 256 + wave * 64) * 8;
    }

    // ---- fragment read offsets (u16 units) ----
    int aoff[WMT], boff[4];
#pragma unroll
    for (int mt = 0; mt < WMT; ++mt) {
        int r = wm * (WMT * 16) + mt * 16 + l16;
        aoff[mt] = r * 32 + (quad ^ ((r >> 1) & 3)) * 8;
    }
#pragma unroll
    for (int nt = 0; nt < 4; ++nt) {
        int r = wn * 64 + nt * 16 + l16;
        boff[nt] = r * 32 + (quad ^ ((r >> 1) & 3)) * 8;
    }

    f32x4 acc[WMT][4];
#pragma unroll
    for (int mt = 0; mt < WMT; ++mt)
#pragma unroll
        for (int nt = 0; nt < 4; ++nt) acc[mt][nt] = (f32x4){0.f, 0.f, 0.f, 0.f};

    for (int k0 = 0; k0 < EE; k0 += 32) {
        __syncthreads();                    // prior readers done
#pragma unroll
        for (int h = 0; h < AHALF; ++h) {
            async_ld16(agh[h] + k0, sAh + aldw[h]);
            async_ld16(agl[h] + k0, sAl + aldw[h]);
        }
#pragma unroll
        for (int h = 0; h < 2; ++h) {
            async_ld16(bgh[h] + k0, sBh + bldw[h]);
            async_ld16(bgl[h] + k0, sBl + bldw[h]);
        }
        __syncthreads();                    // compiler drains vmcnt before barrier

        short8 fah[WMT], fal[WMT], fbh[4], fbl[4];
#pragma unroll
        for (int mt = 0; mt < WMT; ++mt) {
            fah[mt] = *(const short8*)&sAh[aoff[mt]];
            fal[mt] = *(const short8*)&sAl[aoff[mt]];
        }
#pragma unroll
        for (int nt = 0; nt < 4; ++nt) {
            fbh[nt] = *(const short8*)&sBh[boff[nt]];
            fbl[nt] = *(const short8*)&sBl[boff[nt]];
        }
#pragma unroll
        for (int mt = 0; mt < WMT; ++mt)
#pragma unroll
            for (int nt = 0; nt < 4; ++nt) {
                f32x4 c = acc[mt][nt];
                c = __builtin_amdgcn_mfma_f32_16x16x32_bf16(fal[mt], fbh[nt], c, 0, 0, 0);
                c = __builtin_amdgcn_mfma_f32_16x16x32_bf16(fah[mt], fbl[nt], c, 0, 0, 0);
                c = __builtin_amdgcn_mfma_f32_16x16x32_bf16(fah[mt], fbh[nt], c, 0, 0, 0);
                acc[mt][nt] = c;
            }
    }

    // ---- epilogue: bias add, store (C row = quad*4+r, col = l16) ----
    float bv[4];
#pragma unroll
    for (int nt = 0; nt < 4; ++nt) bv[nt] = bias[n0 + wn * 64 + nt * 16 + l16];
#pragma unroll
    for (int mt = 0; mt < WMT; ++mt)
#pragma unroll
        for (int nt = 0; nt < 4; ++nt)
#pragma unroll
            for (int r = 0; r < 4; ++r) {
                int rg = m0 + wm * (WMT * 16) + mt * 16 + quad * 4 + r;
                int cg = n0 + wn * 64 + nt * 16 + l16;
                float v = acc[mt][nt][r] + bv[nt];
                if (BF16OUT) ((u16*)Cout)[(size_t)rg * N + cg] = f2bf(v);
                else         ((float*)Cout)[(size_t)rg * N + cg] = v;
            }
}

// MFMA bf16 flash attention (unchanged from R2 core; epilogue now emits hi/lo bf16).
__global__ __launch_bounds__(256) void attn_mfma(
    const u16* __restrict__ qkv, u16* __restrict__ ohi, u16* __restrict__ olo)
{
    __shared__ u16 Qs[64][72];
    __shared__ u16 Ks[64][72];
    __shared__ u16 Vt[64][72];
    __shared__ u16 Ps[64][72];

    const int tid  = threadIdx.x;
    const int wave = tid >> 6;
    const int lane = tid & 63;
    const int quad = lane >> 4;
    const int l16  = lane & 15;
    const int mq   = wave * 16;

    const int q0 = blockIdx.x * 64;
    const int h  = blockIdx.y;
    const int b  = blockIdx.z;
    const float scale = 0.125f;

    const int ldrow = tid >> 2;
    const int ldc   = (tid & 3) << 4;
    const int vsw = (((ldrow >> 3) ^ (tid & 3)) << 3) | (ldrow & 7);

    {
        const u16* qp = qkv + (size_t)(b * TT + q0 + ldrow) * E3 + h * DD + ldc;
        *(uint4*)&Qs[ldrow][ldc]     = *(const uint4*)qp;
        *(uint4*)&Qs[ldrow][ldc + 8] = *(const uint4*)(qp + 8);
    }

    float m_i[4], l_i[4];
    f32x4 o[4];
#pragma unroll
    for (int r = 0; r < 4; ++r) { m_i[r] = -1e30f; l_i[r] = 0.f; }
#pragma unroll
    for (int dt = 0; dt < 4; ++dt) o[dt] = (f32x4){0.f, 0.f, 0.f, 0.f};

    for (int kt = 0; kt < TT; kt += 64) {
        __syncthreads();
        const u16* kp = qkv + (size_t)(b * TT + kt + ldrow) * E3 + EE + h * DD + ldc;
        uint4 k0v = *(const uint4*)kp;
        uint4 k1v = *(const uint4*)(kp + 8);
        union { uint4 u[2]; u16 s[16]; } vv;
        vv.u[0] = *(const uint4*)(kp + EE);
        vv.u[1] = *(const uint4*)(kp + EE + 8);
        *(uint4*)&Ks[ldrow][ldc]     = k0v;
        *(uint4*)&Ks[ldrow][ldc + 8] = k1v;
#pragma unroll
        for (int j = 0; j < 16; ++j) Vt[ldc + j][vsw] = vv.s[j];
        __syncthreads();

        f32x4 s[4];
#pragma unroll
        for (int nt = 0; nt < 4; ++nt) s[nt] = (f32x4){0.f, 0.f, 0.f, 0.f};
#pragma unroll
        for (int ks = 0; ks < 2; ++ks) {
            short8 aq = *(const short8*)&Qs[mq + l16][ks * 32 + quad * 8];
#pragma unroll
            for (int nt = 0; nt < 4; ++nt) {
                short8 bk = *(const short8*)&Ks[nt * 16 + l16][ks * 32 + quad * 8];
                s[nt] = __builtin_amdgcn_mfma_f32_16x16x32_bf16(aq, bk, s[nt], 0, 0, 0);
            }
        }

#pragma unroll
        for (int r = 0; r < 4; ++r) {
            float mt = fmaxf(fmaxf(s[0][r], s[1][r]), fmaxf(s[2][r], s[3][r])) * scale;
#pragma unroll
            for (int off = 1; off < 16; off <<= 1)
                mt = fmaxf(mt, __shfl_xor(mt, off, 64));
            float mnew = fmaxf(m_i[r], mt);
            float alpha = __expf(m_i[r] - mnew);
            m_i[r] = mnew;
            float p0 = __expf(s[0][r] * scale - mnew);
            float p1 = __expf(s[1][r] * scale - mnew);
            float p2 = __expf(s[2][r] * scale - mnew);
            float p3 = __expf(s[3][r] * scale - mnew);
            float rs = (p0 + p1) + (p2 + p3);
#pragma unroll
            for (int off = 1; off < 16; off <<= 1)
                rs += __shfl_xor(rs, off, 64);
            l_i[r] = l_i[r] * alpha + rs;
            int prow = mq + quad * 4 + r;
            Ps[prow][l16]      = f2bf(p0);
            Ps[prow][16 + l16] = f2bf(p1);
            Ps[prow][32 + l16] = f2bf(p2);
            Ps[prow][48 + l16] = f2bf(p3);
            o[0][r] *= alpha; o[1][r] *= alpha;
            o[2][r] *= alpha; o[3][r] *= alpha;
        }
        __syncthreads();

#pragma unroll
        for (int ks = 0; ks < 2; ++ks) {
            short8 ap = *(const short8*)&Ps[mq + l16][ks * 32 + quad * 8];
#pragma unroll
            for (int dt = 0; dt < 4; ++dt) {
                short8 bv = *(const short8*)&Vt[dt * 16 + l16][ks * 32 + ((quad ^ dt) << 3)];
                o[dt] = __builtin_amdgcn_mfma_f32_16x16x32_bf16(ap, bv, o[dt], 0, 0, 0);
            }
        }
    }

#pragma unroll
    for (int r = 0; r < 4; ++r) {
        float inv = 1.f / l_i[r];
        size_t base = (size_t)(b * TT + q0 + mq + quad * 4 + r) * EE + h * DD;
#pragma unroll
        for (int dt = 0; dt < 4; ++dt) {
            float v = o[dt][r] * inv;
            u16 hh = f2bf(v);
            u16 ll = f2bf(v - bf2f(hh));
            ohi[base + dt * 16 + l16] = hh;
            olo[base + dt * 16 + l16] = ll;
        }
    }
}

extern "C" void kernel_launch(void* const* d_in, const int* in_sizes, int n_in,
                              void* d_out, int out_size, void* d_ws, size_t ws_size,
                              hipStream_t stream)
{
    const float* x     = (const float*)d_in[0];
    const float* qkv_w = (const float*)d_in[1];
    const float* qkv_b = (const float*)d_in[2];
    const float* out_w = (const float*)d_in[3];
    const float* out_b = (const float*)d_in[4];
    float* out = (float*)d_out;

    const size_t NX  = (size_t)NTOK * EE;   // 4.19M
    const size_t NW1 = (size_t)E3 * EE;     // 3.15M
    const size_t NW2 = (size_t)EE * EE;     // 1.05M

    u16* ws   = (u16*)d_ws;
    u16* x_hi = ws;                 // reused as attn_hi after gemm1 consumes x
    u16* x_lo = ws + NX;            // reused as attn_lo
    u16* w1h  = ws + 2 * NX;
    u16* w1l  = w1h + NW1;
    u16* w2h  = w1l + NW1;
    u16* w2l  = w2h + NW2;
    u16* qkvb = w2l + NW2;          // [4096][3072] bf16; total ws = 58.7 MB

    split_hl<<<dim3((NX / 4 + 255) / 256), 256, 0, stream>>>(x, x_hi, x_lo, NX / 4);
    split_hl<<<dim3((NW1 / 4 + 255) / 256), 256, 0, stream>>>(qkv_w, w1h, w1l, NW1 / 4);
    split_hl<<<dim3((NW2 / 4 + 255) / 256), 256, 0, stream>>>(out_w, w2h, w2l, NW2 / 4);

    gemm_hilo_mfma<4, true><<<dim3(E3 / 128, NTOK / 128), 256, 0, stream>>>(
        x_hi, x_lo, w1h, w1l, qkv_b, (void*)qkvb, NTOK, E3);

    attn_mfma<<<dim3(TT / 64, HH, BB), 256, 0, stream>>>(qkvb, x_hi, x_lo);

    gemm_hilo_mfma<2, false><<<dim3(EE / 128, NTOK / 64), 256, 0, stream>>>(
        x_hi, x_lo, w2h, w2l, out_b, (void*)out, NTOK, EE);
}

// Round 4
// 287.496 us; speedup vs baseline: 3.5916x; 1.2351x over previous
//
#include <hip/hip_runtime.h>

#define TT 2048
#define BB 2
#define EE 1024
#define HH 16
#define DD 64
#define E3 3072
#define NTOK 4096

typedef unsigned short u16;
typedef __attribute__((ext_vector_type(8))) short short8;
typedef __attribute__((ext_vector_type(4))) float f32x4;

__device__ __forceinline__ u16 f2bf(float f) {
    union { float f; unsigned u; } v; v.f = f;
    unsigned r = (v.u + 0x7fffu + ((v.u >> 16) & 1u)) >> 16;
    return (u16)r;
}
__device__ __forceinline__ float bf2f(u16 h) {
    union { unsigned u; float f; } v; v.u = ((unsigned)h) << 16; return v.f;
}

// async global->LDS, 16 B per lane; lds ptr must be wave-uniform
__device__ __forceinline__ void async_ld16(const u16* g, const u16* l) {
    auto gp = reinterpret_cast<const __attribute__((address_space(1))) unsigned*>(
        reinterpret_cast<uintptr_t>(g));
    auto lp = reinterpret_cast<__attribute__((address_space(3))) unsigned*>(
        reinterpret_cast<uintptr_t>(l));
    __builtin_amdgcn_global_load_lds(gp, lp, 16, 0, 0);
}

// fp32 -> (hi, lo) bf16 planar split, float4 per thread
__global__ __launch_bounds__(256) void split_hl(
    const float* __restrict__ in, u16* __restrict__ hi, u16* __restrict__ lo, int n4)
{
    int i = blockIdx.x * 256 + threadIdx.x;
    if (i >= n4) return;
    float4 v = ((const float4*)in)[i];
    float vv[4] = {v.x, v.y, v.z, v.w};
    unsigned hp[2], lp[2];
#pragma unroll
    for (int p = 0; p < 2; ++p) {
        u16 h0 = f2bf(vv[2 * p]);
        u16 h1 = f2bf(vv[2 * p + 1]);
        u16 l0 = f2bf(vv[2 * p] - bf2f(h0));
        u16 l1 = f2bf(vv[2 * p + 1] - bf2f(h1));
        hp[p] = (unsigned)h0 | ((unsigned)h1 << 16);
        lp[p] = (unsigned)l0 | ((unsigned)l1 << 16);
    }
    *(uint2*)&hi[(size_t)i * 4] = make_uint2(hp[0], hp[1]);
    *(uint2*)&lo[(size_t)i * 4] = make_uint2(lp[0], lp[1]);
}

// Split-bf16 MFMA GEMM (unchanged from R3):  C = A @ W^T + bias
template <int WMT, bool BF16OUT>
__global__ __launch_bounds__(256) void gemm_hilo_mfma(
    const u16* __restrict__ Ahg, const u16* __restrict__ Alg,
    const u16* __restrict__ Whg, const u16* __restrict__ Wlg,
    const float* __restrict__ bias, void* __restrict__ Cout, int M, int N)
{
    constexpr int BM = WMT * 32;
    constexpr int AHALF = BM / 64;
    __shared__ u16 sAh[BM * 32], sAl[BM * 32];
    __shared__ u16 sBh[128 * 32], sBl[128 * 32];

    const int tid  = threadIdx.x;
    const int lane = tid & 63;
    const int wave = tid >> 6;
    const int quad = lane >> 4;
    const int l16  = lane & 15;
    const int wm = wave >> 1, wn = wave & 1;
    const int m0 = blockIdx.y * BM;
    const int n0 = blockIdx.x * 128;

    const u16* agh[AHALF]; const u16* agl[AHALF]; int aldw[AHALF];
#pragma unroll
    for (int h = 0; h < AHALF; ++h) {
        int s = h * 256 + tid;
        int row = s >> 2, k8p = s & 3;
        int k8 = k8p ^ ((row >> 1) & 3);
        agh[h] = Ahg + (size_t)(m0 + row) * EE + k8 * 8;
        agl[h] = Alg + (size_t)(m0 + row) * EE + k8 * 8;
        aldw[h] = (h * 256 + wave * 64) * 8;
    }
    const u16* bgh[2]; const u16* bgl[2]; int bldw[2];
#pragma unroll
    for (int h = 0; h < 2; ++h) {
        int s = h * 256 + tid;
        int row = s >> 2, k8p = s & 3;
        int k8 = k8p ^ ((row >> 1) & 3);
        bgh[h] = Whg + (size_t)(n0 + row) * EE + k8 * 8;
        bgl[h] = Wlg + (size_t)(n0 + row) * EE + k8 * 8;
        bldw[h] = (h * 256 + wave * 64) * 8;
    }

    int aoff[WMT], boff[4];
#pragma unroll
    for (int mt = 0; mt < WMT; ++mt) {
        int r = wm * (WMT * 16) + mt * 16 + l16;
        aoff[mt] = r * 32 + (quad ^ ((r >> 1) & 3)) * 8;
    }
#pragma unroll
    for (int nt = 0; nt < 4; ++nt) {
        int r = wn * 64 + nt * 16 + l16;
        boff[nt] = r * 32 + (quad ^ ((r >> 1) & 3)) * 8;
    }

    f32x4 acc[WMT][4];
#pragma unroll
    for (int mt = 0; mt < WMT; ++mt)
#pragma unroll
        for (int nt = 0; nt < 4; ++nt) acc[mt][nt] = (f32x4){0.f, 0.f, 0.f, 0.f};

    for (int k0 = 0; k0 < EE; k0 += 32) {
        __syncthreads();
#pragma unroll
        for (int h = 0; h < AHALF; ++h) {
            async_ld16(agh[h] + k0, sAh + aldw[h]);
            async_ld16(agl[h] + k0, sAl + aldw[h]);
        }
#pragma unroll
        for (int h = 0; h < 2; ++h) {
            async_ld16(bgh[h] + k0, sBh + bldw[h]);
            async_ld16(bgl[h] + k0, sBl + bldw[h]);
        }
        __syncthreads();

        short8 fah[WMT], fal[WMT], fbh[4], fbl[4];
#pragma unroll
        for (int mt = 0; mt < WMT; ++mt) {
            fah[mt] = *(const short8*)&sAh[aoff[mt]];
            fal[mt] = *(const short8*)&sAl[aoff[mt]];
        }
#pragma unroll
        for (int nt = 0; nt < 4; ++nt) {
            fbh[nt] = *(const short8*)&sBh[boff[nt]];
            fbl[nt] = *(const short8*)&sBl[boff[nt]];
        }
#pragma unroll
        for (int mt = 0; mt < WMT; ++mt)
#pragma unroll
            for (int nt = 0; nt < 4; ++nt) {
                f32x4 c = acc[mt][nt];
                c = __builtin_amdgcn_mfma_f32_16x16x32_bf16(fal[mt], fbh[nt], c, 0, 0, 0);
                c = __builtin_amdgcn_mfma_f32_16x16x32_bf16(fah[mt], fbl[nt], c, 0, 0, 0);
                c = __builtin_amdgcn_mfma_f32_16x16x32_bf16(fah[mt], fbh[nt], c, 0, 0, 0);
                acc[mt][nt] = c;
            }
    }

    float bv[4];
#pragma unroll
    for (int nt = 0; nt < 4; ++nt) bv[nt] = bias[n0 + wn * 64 + nt * 16 + l16];
#pragma unroll
    for (int mt = 0; mt < WMT; ++mt)
#pragma unroll
        for (int nt = 0; nt < 4; ++nt)
#pragma unroll
            for (int r = 0; r < 4; ++r) {
                int rg = m0 + wm * (WMT * 16) + mt * 16 + quad * 4 + r;
                int cg = n0 + wn * 64 + nt * 16 + l16;
                float v = acc[mt][nt][r] + bv[nt];
                if (BF16OUT) ((u16*)Cout)[(size_t)rg * N + cg] = f2bf(v);
                else         ((float*)Cout)[(size_t)rg * N + cg] = v;
            }
}

// S^T/O^T-formulation MFMA flash attention. 4 waves, 64-query tile.
// S^T = K*Q^T  (C col = q = lane&15  ->  softmax state is PER-LANE)
// O^T = V^T*P^T.  All LDS tiles: [half][64 rows][32 u16] + m97 XOR-chunk swizzle.
__global__ __launch_bounds__(256, 4) void attn_mfma(
    const u16* __restrict__ qkv, u16* __restrict__ ohi, u16* __restrict__ olo)
{
    __shared__ u16 Qh[2][64][32];    // [d-half][q][swz d-chunk]
    __shared__ u16 Kh[2][64][32];    // [d-half][key][swz d-chunk]
    __shared__ u16 Vth[2][64][32];   // [key-half][d][swz key-chunk]
    __shared__ u16 Pth[2][64][32];   // [key-half][q][swz key-chunk]  (wave-private rows)

    const int tid  = threadIdx.x;
    const int wave = tid >> 6;
    const int lane = tid & 63;
    const int quad = lane >> 4;
    const int l16  = lane & 15;
    const int mq   = wave * 16;

    const int q0 = blockIdx.x * 64;
    const int hh = blockIdx.y;
    const int b  = blockIdx.z;
    const float C1 = 0.18033688011112042f;   // 0.125 * log2(e)

    // ---- staging maps ----
    const int grow = tid >> 2;               // row 0..63
    const int gchk = tid & 3;                // chunk slot 0..3
    const int gsw  = (grow >> 1) & 3;        // row swizzle
    const int dlo  = ((gchk ^ gsw) << 3);    // swizzled d offset, pass 0
    const int ldsw = wave * 512;             // wave-uniform LDS u16 offset (pass adds 2048)

    // V-transpose write constants: lane holds key=grow, d = gchk*16 + j
    const int vkh = grow >> 5;
    const int vkc = (grow & 31) >> 3;
    const int vk7 = grow & 7;

    // ---- stage Q once ----
    {
        const u16* qg = qkv + (size_t)(b * TT + q0 + grow) * E3 + hh * DD;
        async_ld16(qg + dlo,      &Qh[0][0][0] + ldsw);
        async_ld16(qg + 32 + dlo, &Qh[0][0][0] + 2048 + ldsw);
    }
    __syncthreads();
    const int fsw = (quad ^ ((l16 >> 1) & 3)) << 3;   // frag-read swizzled chunk
    short8 qb0 = *(const short8*)&Qh[0][mq + l16][fsw];
    short8 qb1 = *(const short8*)&Qh[1][mq + l16][fsw];

    const u16* kg = qkv + (size_t)(b * TT + grow) * E3 + EE + hh * DD;
    const u16* vg = qkv + (size_t)(b * TT + grow) * E3 + 2 * EE + hh * DD + gchk * 16;

    float m2 = -1e30f, l_i = 0.f;            // per-lane (query = mq+l16), exp2 domain
    f32x4 o[4];
#pragma unroll
    for (int dt = 0; dt < 4; ++dt) o[dt] = (f32x4){0.f, 0.f, 0.f, 0.f};

    for (int kt = 0; kt < TT; kt += 64) {
        __syncthreads();                     // prior iter's Kh/Vth readers done
        // K via async glds (swizzle folded into global source index)
        const u16* kgi = kg + (size_t)kt * E3;
        async_ld16(kgi + dlo,      &Kh[0][0][0] + ldsw);
        async_ld16(kgi + 32 + dlo, &Kh[0][0][0] + 2048 + ldsw);
        // V: load 16 d-values for one key, transpose-write (2-way de-aliased)
        union { uint4 u[2]; u16 s[16]; } vv;
        const u16* vgi = vg + (size_t)kt * E3;
        vv.u[0] = *(const uint4*)vgi;
        vv.u[1] = *(const uint4*)(vgi + 8);
#pragma unroll
        for (int j = 0; j < 16; ++j) {
            int phys = vkc ^ ((j >> 1) & 3) ^ gchk;
            Vth[vkh][gchk * 16 + j][phys * 8 + vk7] = vv.s[j];
        }
        __syncthreads();                     // drains vmcnt (glds) + lgkmcnt

        // ---- S^T = K * Q^T : 4 key-tiles of 16, C col = q = l16 ----
        f32x4 s[4];
#pragma unroll
        for (int nt = 0; nt < 4; ++nt) s[nt] = (f32x4){0.f, 0.f, 0.f, 0.f};
#pragma unroll
        for (int nt = 0; nt < 4; ++nt) {
            short8 kf0 = *(const short8*)&Kh[0][nt * 16 + l16][fsw];
            short8 kf1 = *(const short8*)&Kh[1][nt * 16 + l16][fsw];
            s[nt] = __builtin_amdgcn_mfma_f32_16x16x32_bf16(kf0, qb0, s[nt], 0, 0, 0);
            s[nt] = __builtin_amdgcn_mfma_f32_16x16x32_bf16(kf1, qb1, s[nt], 0, 0, 0);
        }

        // ---- per-lane online softmax over this lane's 16 keys ----
        float mt = s[0][0];
#pragma unroll
        for (int nt = 0; nt < 4; ++nt)
#pragma unroll
            for (int r = 0; r < 4; ++r) mt = fmaxf(mt, s[nt][r]);
        mt = fmaxf(mt, __shfl_xor(mt, 16, 64));
        mt = fmaxf(mt, __shfl_xor(mt, 32, 64));
        float m2new = fmaxf(m2, mt * C1);
        float alpha = __builtin_amdgcn_exp2f(m2 - m2new);
        m2 = m2new;

        float p[4][4];
        float rs = 0.f;
#pragma unroll
        for (int nt = 0; nt < 4; ++nt) {
            float pn = 0.f;
#pragma unroll
            for (int r = 0; r < 4; ++r) {
                float pj = __builtin_amdgcn_exp2f(fmaf(s[nt][r], C1, -m2new));
                p[nt][r] = pj;
                // truncated value (== stored bf16) for a consistent denominator
                pn += __uint_as_float(__float_as_uint(pj) & 0xffff0000u);
            }
            rs += pn;
        }
        rs += __shfl_xor(rs, 16, 64);
        rs += __shfl_xor(rs, 32, 64);
        l_i = l_i * alpha + rs;

        // pack P^T (truncation = take hi16) and store: wave-private rows, no barrier
#pragma unroll
        for (int nt = 0; nt < 4; ++nt) {
            unsigned lo32 = __builtin_amdgcn_perm(
                __float_as_uint(p[nt][1]), __float_as_uint(p[nt][0]), 0x07060302u);
            unsigned hi32 = __builtin_amdgcn_perm(
                __float_as_uint(p[nt][3]), __float_as_uint(p[nt][2]), 0x07060302u);
            int phys = ((((nt & 1) << 1) | (quad >> 1)) ^ ((l16 >> 1) & 3));
            *(uint2*)&Pth[nt >> 1][mq + l16][phys * 8 + ((quad & 1) << 2)] =
                make_uint2(lo32, hi32);
        }

        // rescale O^T (alpha is per-lane uniform)
#pragma unroll
        for (int dt = 0; dt < 4; ++dt)
#pragma unroll
            for (int r = 0; r < 4; ++r) o[dt][r] *= alpha;

        // ---- O^T += V^T * P^T ----
#pragma unroll
        for (int ks = 0; ks < 2; ++ks) {
            short8 pb = *(const short8*)&Pth[ks][mq + l16][fsw];
#pragma unroll
            for (int dt = 0; dt < 4; ++dt) {
                short8 vf = *(const short8*)&Vth[ks][dt * 16 + l16]
                    [((quad ^ ((l16 >> 1) & 3) ^ dt) << 3)];
                o[dt] = __builtin_amdgcn_mfma_f32_16x16x32_bf16(vf, pb, o[dt], 0, 0, 0);
            }
        }
    }

    // ---- epilogue: normalize, emit hi/lo bf16 for the out-proj GEMM ----
    float inv = 1.f / l_i;
    size_t base = (size_t)(b * TT + q0 + mq + l16) * EE + hh * DD;
#pragma unroll
    for (int dt = 0; dt < 4; ++dt) {
        u16 hv[4], lv[4];
#pragma unroll
        for (int r = 0; r < 4; ++r) {
            float v = o[dt][r] * inv;
            hv[r] = f2bf(v);
            lv[r] = f2bf(v - bf2f(hv[r]));
        }
        size_t off = base + dt * 16 + quad * 4;
        *(uint2*)&ohi[off] = make_uint2((unsigned)hv[0] | ((unsigned)hv[1] << 16),
                                        (unsigned)hv[2] | ((unsigned)hv[3] << 16));
        *(uint2*)&olo[off] = make_uint2((unsigned)lv[0] | ((unsigned)lv[1] << 16),
                                        (unsigned)lv[2] | ((unsigned)lv[3] << 16));
    }
}

extern "C" void kernel_launch(void* const* d_in, const int* in_sizes, int n_in,
                              void* d_out, int out_size, void* d_ws, size_t ws_size,
                              hipStream_t stream)
{
    const float* x     = (const float*)d_in[0];
    const float* qkv_w = (const float*)d_in[1];
    const float* qkv_b = (const float*)d_in[2];
    const float* out_w = (const float*)d_in[3];
    const float* out_b = (const float*)d_in[4];
    float* out = (float*)d_out;

    const size_t NX  = (size_t)NTOK * EE;
    const size_t NW1 = (size_t)E3 * EE;
    const size_t NW2 = (size_t)EE * EE;

    u16* ws   = (u16*)d_ws;
    u16* x_hi = ws;                 // reused as attn_hi after gemm1 consumes x
    u16* x_lo = ws + NX;            // reused as attn_lo
    u16* w1h  = ws + 2 * NX;
    u16* w1l  = w1h + NW1;
    u16* w2h  = w1l + NW1;
    u16* w2l  = w2h + NW2;
    u16* qkvb = w2l + NW2;

    split_hl<<<dim3((NX / 4 + 255) / 256), 256, 0, stream>>>(x, x_hi, x_lo, NX / 4);
    split_hl<<<dim3((NW1 / 4 + 255) / 256), 256, 0, stream>>>(qkv_w, w1h, w1l, NW1 / 4);
    split_hl<<<dim3((NW2 / 4 + 255) / 256), 256, 0, stream>>>(out_w, w2h, w2l, NW2 / 4);

    gemm_hilo_mfma<4, true><<<dim3(E3 / 128, NTOK / 128), 256, 0, stream>>>(
        x_hi, x_lo, w1h, w1l, qkv_b, (void*)qkvb, NTOK, E3);

    attn_mfma<<<dim3(TT / 64, HH, BB), 256, 0, stream>>>(qkvb, x_hi, x_lo);

    gemm_hilo_mfma<2, false><<<dim3(EE / 128, NTOK / 64), 256, 0, stream>>>(
        x_hi, x_lo, w2h, w2l, out_b, (void*)out, NTOK, EE);
}